// Round 1
// baseline (373.748 us; speedup 1.0000x reference)
//
#include <hip/hip_runtime.h>
#include <math.h>

#define BM 128
#define BN 128
#define BK 8
#define TM 8
#define TN 8

// Generic fp32 GEMM: C[M,N] = A[M,K] @ W[K,N] + bias[N]
// A row-major (lda=K), W row-major (ldw=N), C row-major (ldc=N).
// Guards rows (M any) and cols (N multiple of 4).
__global__ __launch_bounds__(256) void gemm_f32(
    const float* __restrict__ A, const float* __restrict__ W,
    const float* __restrict__ bias, float* __restrict__ C,
    int M, int N, int K) {
  __shared__ float As[BK][BM + 4];
  __shared__ float Bs[BK][BN + 4];
  const int tid = threadIdx.x;
  const int bm = blockIdx.y, bn = blockIdx.x;
  const int tr = tid >> 4, tc = tid & 15;  // 16x16 thread grid, 8x8 per thread

  float acc[TM][TN];
#pragma unroll
  for (int i = 0; i < TM; i++)
#pragma unroll
    for (int j = 0; j < TN; j++) acc[i][j] = 0.f;

  // A-tile load: 128x8 = 1024 floats, 256 thr -> 1 float4 each.
  int arow = bm * BM + (tid >> 1);
  int arow_c = arow < M ? arow : (M - 1);
  const float* Aptr = A + (size_t)arow_c * K + ((tid & 1) << 2);
  // B-tile load: 8x128 -> 1 float4 each.
  int bcol = bn * BN + ((tid & 31) << 2);
  const bool bvalid = bcol < N;
  const float* Wptr = W + (size_t)(tid >> 5) * N + bcol;

  for (int k0 = 0; k0 < K; k0 += BK) {
    float4 av = *(const float4*)(Aptr + k0);
    float4 bv = bvalid ? *(const float4*)(Wptr + (size_t)k0 * N)
                       : make_float4(0.f, 0.f, 0.f, 0.f);
    __syncthreads();
    As[(tid & 1) * 4 + 0][tid >> 1] = av.x;
    As[(tid & 1) * 4 + 1][tid >> 1] = av.y;
    As[(tid & 1) * 4 + 2][tid >> 1] = av.z;
    As[(tid & 1) * 4 + 3][tid >> 1] = av.w;
    *(float4*)&Bs[tid >> 5][(tid & 31) << 2] = bv;
    __syncthreads();
#pragma unroll
    for (int k = 0; k < BK; k++) {
      float ar[TM], br[TN];
      *(float4*)&ar[0] = *(const float4*)&As[k][tr * TM];
      *(float4*)&ar[4] = *(const float4*)&As[k][tr * TM + 4];
      *(float4*)&br[0] = *(const float4*)&Bs[k][tc * TN];
      *(float4*)&br[4] = *(const float4*)&Bs[k][tc * TN + 4];
#pragma unroll
      for (int i = 0; i < TM; i++)
#pragma unroll
        for (int j = 0; j < TN; j++) acc[i][j] = fmaf(ar[i], br[j], acc[i][j]);
    }
  }

#pragma unroll
  for (int i = 0; i < TM; i++) {
    int row = bm * BM + tr * TM + i;
    if (row >= M) continue;
    float* Crow = C + (size_t)row * N;
#pragma unroll
    for (int j = 0; j < TN; j += 4) {
      int col = bn * BN + tc * TN + j;
      if (col < N) {
        float4 o;
        o.x = acc[i][j + 0] + bias[col + 0];
        o.y = acc[i][j + 1] + bias[col + 1];
        o.z = acc[i][j + 2] + bias[col + 2];
        o.w = acc[i][j + 3] + bias[col + 3];
        *(float4*)(Crow + col) = o;
      }
    }
  }
}

// Concatenate offsets_w (256x192) and attn_w (256x96) -> Wcat (256x288); same for bias.
__global__ void build_wcat(const float* __restrict__ offw, const float* __restrict__ offb,
                           const float* __restrict__ attnw, const float* __restrict__ attnb,
                           float* __restrict__ Wcat, float* __restrict__ bcat) {
  int idx = blockIdx.x * 256 + threadIdx.x;
  if (idx < 256 * 288) {
    int k = idx / 288, n = idx % 288;
    Wcat[idx] = (n < 192) ? offw[k * 192 + n] : attnw[k * 96 + (n - 192)];
  }
  if (idx < 288) bcat[idx] = (idx < 192) ? offb[idx] : attnb[idx - 192];
}

// One block per (b,q). 8 heads x 32 lanes. Softmax over 12 logits per head,
// 12 bilinear samples per head, weighted accumulate -> attn_out[bq][256].
__global__ __launch_bounds__(256) void ms_deform_sample(
    const float* __restrict__ value,   // (B*8400, 256), c = h*32+d
    const float* __restrict__ offaw,   // (B*300, 288): 192 offsets + 96 logits
    const float* __restrict__ refp,    // (B,300,3,4)
    float* __restrict__ attn_out) {    // (B*300, 256)
  const int bq = blockIdx.x;
  const int b = bq / 300;
  const int h = threadIdx.x >> 5;
  const int d = threadIdx.x & 31;
  const float* row = offaw + (size_t)bq * 288;

  // softmax over L*P = 12
  float lg[12];
#pragma unroll
  for (int j = 0; j < 12; j++) lg[j] = row[192 + h * 12 + j];
  float m = lg[0];
#pragma unroll
  for (int j = 1; j < 12; j++) m = fmaxf(m, lg[j]);
  float s = 0.f;
#pragma unroll
  for (int j = 0; j < 12; j++) { lg[j] = __expf(lg[j] - m); s += lg[j]; }
  const float inv = 1.f / s;

  const int lvlHW[3] = {80, 40, 20};
  const int lvlS[3] = {0, 6400, 8000};
  const float* ref = refp + (size_t)bq * 12;
  float acc = 0.f;

#pragma unroll
  for (int l = 0; l < 3; l++) {
    const int Hs = lvlHW[l], Ws = lvlHW[l], st = lvlS[l];
    const float r0 = ref[l * 4 + 0], r1 = ref[l * 4 + 1];
    const float r2 = ref[l * 4 + 2], r3 = ref[l * 4 + 3];
    const float* vbase = value + ((size_t)(b * 8400 + st) * 256) + h * 32 + d;
#pragma unroll
    for (int p = 0; p < 4; p++) {
      const float ox = row[h * 24 + l * 8 + p * 2 + 0];
      const float oy = row[h * 24 + l * 8 + p * 2 + 1];
      const float x = (r0 + ox * 0.125f * r2) * (float)Ws - 0.5f;
      const float y = (r1 + oy * 0.125f * r3) * (float)Hs - 0.5f;
      const float x0f = floorf(x), y0f = floorf(y);
      const float wx = x - x0f, wy = y - y0f;
      const int x0 = (int)x0f, y0 = (int)y0f;
      const int x0c = min(max(x0, 0), Ws - 1), x1c = min(max(x0 + 1, 0), Ws - 1);
      const int y0c = min(max(y0, 0), Hs - 1), y1c = min(max(y0 + 1, 0), Hs - 1);
      const bool vx0 = (x0 >= 0) & (x0 < Ws), vx1 = (x0 + 1 >= 0) & (x0 + 1 < Ws);
      const bool vy0 = (y0 >= 0) & (y0 < Hs), vy1 = (y0 + 1 >= 0) & (y0 + 1 < Hs);
      float v00 = 0.f, v01 = 0.f, v10 = 0.f, v11 = 0.f;
      if (vy0) {
        const float* r = vbase + (size_t)(y0c * Ws) * 256;
        if (vx0) v00 = r[(size_t)x0c * 256];
        if (vx1) v01 = r[(size_t)x1c * 256];
      }
      if (vy1) {
        const float* r = vbase + (size_t)(y1c * Ws) * 256;
        if (vx0) v10 = r[(size_t)x0c * 256];
        if (vx1) v11 = r[(size_t)x1c * 256];
      }
      const float sample = v00 * (1.f - wx) * (1.f - wy) + v01 * wx * (1.f - wy) +
                           v10 * (1.f - wx) * wy + v11 * wx * wy;
      acc = fmaf(lg[l * 4 + p] * inv, sample, acc);
    }
  }
  attn_out[(size_t)bq * 256 + h * 32 + d] = acc;
}

extern "C" void kernel_launch(void* const* d_in, const int* in_sizes, int n_in,
                              void* d_out, int out_size, void* d_ws, size_t ws_size,
                              hipStream_t stream) {
  const float* hidden = (const float*)d_in[0];   // (16,300,256)
  const float* ehs    = (const float*)d_in[1];   // (16,8400,256)
  const float* refp   = (const float*)d_in[2];   // (16,300,3,4)
  const float* vw     = (const float*)d_in[3];   // (256,256)
  const float* vb     = (const float*)d_in[4];
  const float* offw   = (const float*)d_in[5];   // (256,192)
  const float* offb   = (const float*)d_in[6];
  const float* attnw  = (const float*)d_in[7];   // (256,96)
  const float* attnb  = (const float*)d_in[8];
  const float* outw   = (const float*)d_in[9];   // (256,256)
  const float* outb   = (const float*)d_in[10];
  float* out = (float*)d_out;

  float* ws = (float*)d_ws;
  float* value  = ws;                        // 134400*256 = 34406400 floats
  float* Wcat   = value + 34406400;          // 73728
  float* bcat   = Wcat + 73728;              // 512 (288 used)
  float* offaw  = bcat + 512;                // 4800*288 = 1382400
  float* attn_o = offaw + 1382400;           // 4800*256 = 1228800

  // 1) value = ehs @ vw + vb   (M=134400, N=256, K=256)
  gemm_f32<<<dim3(2, 1050), 256, 0, stream>>>(ehs, vw, vb, value, 134400, 256, 256);
  // 2) concat weights, then offaw = hidden @ Wcat + bcat (M=4800, N=288, K=256)
  build_wcat<<<288, 256, 0, stream>>>(offw, offb, attnw, attnb, Wcat, bcat);
  gemm_f32<<<dim3(3, 38), 256, 0, stream>>>(hidden, Wcat, bcat, offaw, 4800, 288, 256);
  // 3) deformable sampling + softmax-weighted sum
  ms_deform_sample<<<4800, 256, 0, stream>>>(value, offaw, refp, attn_o);
  // 4) out = attn_o @ outw + outb (M=4800, N=256, K=256)
  gemm_f32<<<dim3(2, 38), 256, 0, stream>>>(attn_o, outw, outb, out, 4800, 256, 256);
}

// Round 2
// 269.834 us; speedup vs baseline: 1.3851x; 1.3851x over previous
//
#include <hip/hip_runtime.h>
#include <math.h>

typedef unsigned short u16;
typedef __attribute__((ext_vector_type(8))) short short8;
typedef __attribute__((ext_vector_type(4))) float f32x4;

static __device__ __forceinline__ u16 f2bf(float f) {
  union { float f; unsigned u; } v; v.f = f;
  unsigned u = v.u;
  return (u16)((u + 0x7FFFu + ((u >> 16) & 1u)) >> 16);
}
static __device__ __forceinline__ float bf2f(u16 u) {
  union { unsigned u; float f; } v; v.u = ((unsigned)u) << 16;
  return v.f;
}

// ---------------- value GEMM: C_bf16[M,256] = A_f32[M,256] @ Wt_bf16^T + bias ----
// Wt is pre-transposed: Wt[n][k] (256x256 bf16). M=134400 (mult of 128).
// 128x128 tile, 4 waves (2x2), BK=64, mfma_f32_16x16x32_bf16.
// LDS XOR swizzle: ushort index k ^ ((row&7)*8), applied on write AND read.
__global__ __launch_bounds__(256) void gemm_value_bf16(
    const float* __restrict__ A, const u16* __restrict__ Wt,
    const float* __restrict__ bias, u16* __restrict__ C) {
  const int m0 = blockIdx.y * 128;
  const int n0 = blockIdx.x * 128;
  __shared__ u16 As[128 * 64];
  __shared__ u16 Bs[128 * 64];
  const int tid = threadIdx.x;
  const int lane = tid & 63;
  const int w = tid >> 6;
  const int wrow = w >> 1, wcol = w & 1;

  f32x4 acc[4][4];
#pragma unroll
  for (int i = 0; i < 4; i++)
#pragma unroll
    for (int j = 0; j < 4; j++)
#pragma unroll
      for (int r = 0; r < 4; r++) acc[i][j][r] = 0.f;

  const int sr = tid >> 1;           // staging row 0..127
  const int skc = (tid & 1) * 32;    // ushort col offset within 64
  const int swz = (sr & 7) * 8;      // XOR swizzle (ushort units)
  const float* aptr = A + (size_t)(m0 + sr) * 256 + skc;
  const u16* bptr = Wt + (size_t)(n0 + sr) * 256 + skc;
  u16* adst = &As[sr * 64];
  u16* bdst = &Bs[sr * 64];

  for (int k0 = 0; k0 < 256; k0 += 64) {
    float4 av[8];
    const float4* a4 = (const float4*)(aptr + k0);
#pragma unroll
    for (int j = 0; j < 8; j++) av[j] = a4[j];
    short8 bv[4];
    const short8* b8 = (const short8*)(bptr + k0);
#pragma unroll
    for (int j = 0; j < 4; j++) bv[j] = b8[j];

    __syncthreads();
    u16 at[32];
#pragma unroll
    for (int j = 0; j < 8; j++) {
      at[j * 4 + 0] = f2bf(av[j].x);
      at[j * 4 + 1] = f2bf(av[j].y);
      at[j * 4 + 2] = f2bf(av[j].z);
      at[j * 4 + 3] = f2bf(av[j].w);
    }
#pragma unroll
    for (int j = 0; j < 4; j++)
      *(short8*)&adst[(skc + j * 8) ^ swz] = *(short8*)&at[j * 8];
#pragma unroll
    for (int j = 0; j < 4; j++)
      *(short8*)&bdst[(skc + j * 8) ^ swz] = bv[j];
    __syncthreads();

#pragma unroll
    for (int kk = 0; kk < 64; kk += 32) {
      const int kb = kk + ((lane >> 4) << 3);
      short8 af[4], bfr[4];
#pragma unroll
      for (int i = 0; i < 4; i++) {
        const int row = wrow * 64 + i * 16 + (lane & 15);
        af[i] = *(const short8*)&As[row * 64 + (kb ^ ((row & 7) * 8))];
      }
#pragma unroll
      for (int j = 0; j < 4; j++) {
        const int nr = wcol * 64 + j * 16 + (lane & 15);
        bfr[j] = *(const short8*)&Bs[nr * 64 + (kb ^ ((nr & 7) * 8))];
      }
#pragma unroll
      for (int i = 0; i < 4; i++)
#pragma unroll
        for (int j = 0; j < 4; j++)
          acc[i][j] = __builtin_amdgcn_mfma_f32_16x16x32_bf16(af[i], bfr[j], acc[i][j], 0, 0, 0);
    }
  }

#pragma unroll
  for (int i = 0; i < 4; i++) {
    const int rbase = m0 + wrow * 64 + i * 16 + ((lane >> 4) << 2);
#pragma unroll
    for (int j = 0; j < 4; j++) {
      const int col = n0 + wcol * 64 + j * 16 + (lane & 15);
      const float bc = bias[col];
#pragma unroll
      for (int r = 0; r < 4; r++)
        C[(size_t)(rbase + r) * 256 + col] = f2bf(acc[i][j][r] + bc);
    }
  }
}

// transpose+convert vw (256x256 f32, [k][n]) -> Wt (256x256 bf16, [n][k])
__global__ void convert_wt(const float* __restrict__ vw, u16* __restrict__ Wt) {
  int idx = blockIdx.x * 256 + threadIdx.x;  // 65536
  int n = idx >> 8, k = idx & 255;
  Wt[n * 256 + k] = f2bf(vw[k * 256 + n]);
}

// ---------------- small fp32 GEMM (unchanged) --------------------------------
#define BM 128
#define BN 128
#define BK 8
#define TM 8
#define TN 8
__global__ __launch_bounds__(256) void gemm_f32(
    const float* __restrict__ A, const float* __restrict__ W,
    const float* __restrict__ bias, float* __restrict__ C,
    int M, int N, int K) {
  __shared__ float As[BK][BM + 4];
  __shared__ float Bs[BK][BN + 4];
  const int tid = threadIdx.x;
  const int bm = blockIdx.y, bn = blockIdx.x;
  const int tr = tid >> 4, tc = tid & 15;

  float acc[TM][TN];
#pragma unroll
  for (int i = 0; i < TM; i++)
#pragma unroll
    for (int j = 0; j < TN; j++) acc[i][j] = 0.f;

  int arow = bm * BM + (tid >> 1);
  int arow_c = arow < M ? arow : (M - 1);
  const float* Aptr = A + (size_t)arow_c * K + ((tid & 1) << 2);
  int bcol = bn * BN + ((tid & 31) << 2);
  const bool bvalid = bcol < N;
  const float* Wptr = W + (size_t)(tid >> 5) * N + bcol;

  for (int k0 = 0; k0 < K; k0 += BK) {
    float4 av = *(const float4*)(Aptr + k0);
    float4 bv = bvalid ? *(const float4*)(Wptr + (size_t)k0 * N)
                       : make_float4(0.f, 0.f, 0.f, 0.f);
    __syncthreads();
    As[(tid & 1) * 4 + 0][tid >> 1] = av.x;
    As[(tid & 1) * 4 + 1][tid >> 1] = av.y;
    As[(tid & 1) * 4 + 2][tid >> 1] = av.z;
    As[(tid & 1) * 4 + 3][tid >> 1] = av.w;
    *(float4*)&Bs[tid >> 5][(tid & 31) << 2] = bv;
    __syncthreads();
#pragma unroll
    for (int k = 0; k < BK; k++) {
      float ar[TM], br[TN];
      *(float4*)&ar[0] = *(const float4*)&As[k][tr * TM];
      *(float4*)&ar[4] = *(const float4*)&As[k][tr * TM + 4];
      *(float4*)&br[0] = *(const float4*)&Bs[k][tc * TN];
      *(float4*)&br[4] = *(const float4*)&Bs[k][tc * TN + 4];
#pragma unroll
      for (int i = 0; i < TM; i++)
#pragma unroll
        for (int j = 0; j < TN; j++) acc[i][j] = fmaf(ar[i], br[j], acc[i][j]);
    }
  }

#pragma unroll
  for (int i = 0; i < TM; i++) {
    int row = bm * BM + tr * TM + i;
    if (row >= M) continue;
    float* Crow = C + (size_t)row * N;
#pragma unroll
    for (int j = 0; j < TN; j += 4) {
      int col = bn * BN + tc * TN + j;
      if (col < N) {
        float4 o;
        o.x = acc[i][j + 0] + bias[col + 0];
        o.y = acc[i][j + 1] + bias[col + 1];
        o.z = acc[i][j + 2] + bias[col + 2];
        o.w = acc[i][j + 3] + bias[col + 3];
        *(float4*)(Crow + col) = o;
      }
    }
  }
}

__global__ void build_wcat(const float* __restrict__ offw, const float* __restrict__ offb,
                           const float* __restrict__ attnw, const float* __restrict__ attnb,
                           float* __restrict__ Wcat, float* __restrict__ bcat) {
  int idx = blockIdx.x * 256 + threadIdx.x;
  if (idx < 256 * 288) {
    int k = idx / 288, n = idx % 288;
    Wcat[idx] = (n < 192) ? offw[k * 192 + n] : attnw[k * 96 + (n - 192)];
  }
  if (idx < 288) bcat[idx] = (idx < 192) ? offb[idx] : attnb[idx - 192];
}

// ---------------- deformable sampling (value now bf16) -----------------------
__global__ __launch_bounds__(256) void ms_deform_sample(
    const u16* __restrict__ value,     // (B*8400, 256) bf16, c = h*32+d
    const float* __restrict__ offaw,   // (B*300, 288)
    const float* __restrict__ refp,    // (B,300,3,4)
    float* __restrict__ attn_out) {    // (B*300, 256)
  const int bq = blockIdx.x;
  const int b = bq / 300;
  const int h = threadIdx.x >> 5;
  const int d = threadIdx.x & 31;
  const float* row = offaw + (size_t)bq * 288;

  float lg[12];
#pragma unroll
  for (int j = 0; j < 12; j++) lg[j] = row[192 + h * 12 + j];
  float m = lg[0];
#pragma unroll
  for (int j = 1; j < 12; j++) m = fmaxf(m, lg[j]);
  float s = 0.f;
#pragma unroll
  for (int j = 0; j < 12; j++) { lg[j] = __expf(lg[j] - m); s += lg[j]; }
  const float inv = 1.f / s;

  const int lvlHW[3] = {80, 40, 20};
  const int lvlS[3] = {0, 6400, 8000};
  const float* ref = refp + (size_t)bq * 12;
  float acc = 0.f;

#pragma unroll
  for (int l = 0; l < 3; l++) {
    const int Hs = lvlHW[l], Ws = lvlHW[l], st = lvlS[l];
    const float r0 = ref[l * 4 + 0], r1 = ref[l * 4 + 1];
    const float r2 = ref[l * 4 + 2], r3 = ref[l * 4 + 3];
    const u16* vbase = value + ((size_t)(b * 8400 + st) * 256) + h * 32 + d;
#pragma unroll
    for (int p = 0; p < 4; p++) {
      const float ox = row[h * 24 + l * 8 + p * 2 + 0];
      const float oy = row[h * 24 + l * 8 + p * 2 + 1];
      const float x = (r0 + ox * 0.125f * r2) * (float)Ws - 0.5f;
      const float y = (r1 + oy * 0.125f * r3) * (float)Hs - 0.5f;
      const float x0f = floorf(x), y0f = floorf(y);
      const float wx = x - x0f, wy = y - y0f;
      const int x0 = (int)x0f, y0 = (int)y0f;
      const int x0c = min(max(x0, 0), Ws - 1), x1c = min(max(x0 + 1, 0), Ws - 1);
      const int y0c = min(max(y0, 0), Hs - 1), y1c = min(max(y0 + 1, 0), Hs - 1);
      const bool vx0 = (x0 >= 0) & (x0 < Ws), vx1 = (x0 + 1 >= 0) & (x0 + 1 < Ws);
      const bool vy0 = (y0 >= 0) & (y0 < Hs), vy1 = (y0 + 1 >= 0) & (y0 + 1 < Hs);
      float v00 = 0.f, v01 = 0.f, v10 = 0.f, v11 = 0.f;
      if (vy0) {
        const u16* r = vbase + (size_t)(y0c * Ws) * 256;
        if (vx0) v00 = bf2f(r[(size_t)x0c * 256]);
        if (vx1) v01 = bf2f(r[(size_t)x1c * 256]);
      }
      if (vy1) {
        const u16* r = vbase + (size_t)(y1c * Ws) * 256;
        if (vx0) v10 = bf2f(r[(size_t)x0c * 256]);
        if (vx1) v11 = bf2f(r[(size_t)x1c * 256]);
      }
      const float sample = v00 * (1.f - wx) * (1.f - wy) + v01 * wx * (1.f - wy) +
                           v10 * (1.f - wx) * wy + v11 * wx * wy;
      acc = fmaf(lg[l * 4 + p] * inv, sample, acc);
    }
  }
  attn_out[(size_t)bq * 256 + h * 32 + d] = acc;
}

extern "C" void kernel_launch(void* const* d_in, const int* in_sizes, int n_in,
                              void* d_out, int out_size, void* d_ws, size_t ws_size,
                              hipStream_t stream) {
  const float* hidden = (const float*)d_in[0];
  const float* ehs    = (const float*)d_in[1];
  const float* refp   = (const float*)d_in[2];
  const float* vw     = (const float*)d_in[3];
  const float* vb     = (const float*)d_in[4];
  const float* offw   = (const float*)d_in[5];
  const float* offb   = (const float*)d_in[6];
  const float* attnw  = (const float*)d_in[7];
  const float* attnb  = (const float*)d_in[8];
  const float* outw   = (const float*)d_in[9];
  const float* outb   = (const float*)d_in[10];
  float* out = (float*)d_out;

  u16* value = (u16*)d_ws;                         // 134400*256 bf16
  float* rest = (float*)(value + 34406400);
  float* Wcat   = rest;                            // 73728
  float* bcat   = Wcat + 73728;                    // 512
  float* offaw  = bcat + 512;                      // 1382400
  float* attn_o = offaw + 1382400;                 // 1228800
  u16* Wt = (u16*)(attn_o + 1228800);              // 65536 bf16

  convert_wt<<<256, 256, 0, stream>>>(vw, Wt);
  gemm_value_bf16<<<dim3(2, 1050), 256, 0, stream>>>(ehs, Wt, vb, value);
  build_wcat<<<288, 256, 0, stream>>>(offw, offb, attnw, attnb, Wcat, bcat);
  gemm_f32<<<dim3(3, 38), 256, 0, stream>>>(hidden, Wcat, bcat, offaw, 4800, 288, 256);
  ms_deform_sample<<<4800, 256, 0, stream>>>(value, offaw, refp, attn_o);
  gemm_f32<<<dim3(2, 38), 256, 0, stream>>>(attn_o, outw, outb, out, 4800, 256, 256);
}

// Round 4
// 154.445 us; speedup vs baseline: 2.4199x; 1.7471x over previous
//
#include <hip/hip_runtime.h>
#include <math.h>

typedef unsigned short u16;
typedef __attribute__((ext_vector_type(8))) short short8;
typedef __attribute__((ext_vector_type(4))) short short4v;
typedef __attribute__((ext_vector_type(4))) float f32x4;

static __device__ __forceinline__ u16 f2bf(float f) {
  union { float f; unsigned u; } v; v.f = f;
  unsigned u = v.u;
  return (u16)((u + 0x7FFFu + ((u >> 16) & 1u)) >> 16);
}
static __device__ __forceinline__ float bf2f(u16 u) {
  union { unsigned u; float f; } v; v.u = ((unsigned)u) << 16;
  return v.f;
}

// ---------------------------------------------------------------------------
// prep: WtV/outwT = transposed bf16 weights; Wcat f32 (256x288) + bcat.
// ---------------------------------------------------------------------------
__global__ void prep_weights(const float* __restrict__ vw,
                             const float* __restrict__ offw, const float* __restrict__ attnw,
                             const float* __restrict__ offb, const float* __restrict__ attnb,
                             const float* __restrict__ outw,
                             u16* __restrict__ WtV, u16* __restrict__ outwT,
                             float* __restrict__ Wcat, float* __restrict__ bcat) {
  int idx = blockIdx.x * 256 + threadIdx.x;  // grid 384 -> 98304
  if (idx < 65536) {
    int n = idx >> 8, k = idx & 255;
    WtV[n * 256 + k] = f2bf(vw[k * 256 + n]);
    outwT[n * 256 + k] = f2bf(outw[k * 256 + n]);
  }
  if (idx < 73728) {
    int kk = idx / 288, nn = idx % 288;
    Wcat[idx] = (nn < 192) ? offw[kk * 192 + nn] : attnw[kk * 96 + (nn - 192)];
  }
  if (idx < 288) bcat[idx] = (idx < 192) ? offb[idx] : attnb[idx - 192];
}

// ---------------------------------------------------------------------------
// MFMA GEMM (K=256): AKIND 0: A f32 (convert in staging); AKIND 1: A bf16.
// CKIND 0: C bf16 ldc=256, LDS-repacked dwordx4 stores; CKIND 1: C f32 guarded.
// 128x128 tile, 4 waves, BK=64, XOR swizzle via swizzled global source.
// ---------------------------------------------------------------------------
template <int AKIND, int CKIND, bool GUARD>
__global__ __launch_bounds__(256) void gemm_mfma(
    const void* __restrict__ Ap, const u16* __restrict__ Wt,
    const float* __restrict__ bias, void* __restrict__ Cp,
    int M, int Ncols) {
  const int m0 = blockIdx.y * 128, n0 = blockIdx.x * 128;
  __shared__ u16 smem[2 * 128 * 64];
  u16* As = smem;
  u16* Bs = smem + 128 * 64;
  const int tid = threadIdx.x, lane = tid & 63, w = tid >> 6;
  const int wrow = w >> 1, wcol = w & 1;
  const int r8 = tid >> 3, c8 = tid & 7;
  const int swzB = (c8 ^ (r8 & 7)) * 8;
  const int arow_t = tid >> 4, acol4 = (tid & 15) * 4;
  const int aswz = (arow_t & 7) * 8;

  f32x4 acc[4][4];
#pragma unroll
  for (int i = 0; i < 4; i++)
#pragma unroll
    for (int j = 0; j < 4; j++)
#pragma unroll
      for (int r = 0; r < 4; r++) acc[i][j][r] = 0.f;

#pragma unroll
  for (int t = 0; t < 4; t++) {
    const int k0 = t * 64;
    float4 av[8];
    short8 av16[4];
    short8 bv[4];
    if (AKIND == 0) {
      const float* A = (const float*)Ap;
#pragma unroll
      for (int p = 0; p < 8; p++) {
        int row = m0 + arow_t + p * 16;
        if (GUARD) row = row < M ? row : (M - 1);
        av[p] = *(const float4*)(A + (size_t)row * 256 + k0 + acol4);
      }
    } else {
      const u16* A = (const u16*)Ap;
#pragma unroll
      for (int c = 0; c < 4; c++)
        av16[c] = *(const short8*)(A + (size_t)(m0 + c * 32 + r8) * 256 + k0 + swzB);
    }
#pragma unroll
    for (int c = 0; c < 4; c++)
      bv[c] = *(const short8*)(Wt + (size_t)(n0 + c * 32 + r8) * 256 + k0 + swzB);

    __syncthreads();
    if (AKIND == 0) {
#pragma unroll
      for (int p = 0; p < 8; p++) {
        short4v sv;
        sv[0] = (short)f2bf(av[p].x);
        sv[1] = (short)f2bf(av[p].y);
        sv[2] = (short)f2bf(av[p].z);
        sv[3] = (short)f2bf(av[p].w);
        *(short4v*)&As[(arow_t + p * 16) * 64 + (acol4 ^ aswz)] = sv;
      }
    } else {
#pragma unroll
      for (int c = 0; c < 4; c++)
        *(short8*)&As[(c * 256 + tid) * 8] = av16[c];
    }
#pragma unroll
    for (int c = 0; c < 4; c++)
      *(short8*)&Bs[(c * 256 + tid) * 8] = bv[c];
    __syncthreads();

#pragma unroll
    for (int kk = 0; kk < 64; kk += 32) {
      const int kb = kk + ((lane >> 4) << 3);
      short8 af[4], bfr[4];
#pragma unroll
      for (int i = 0; i < 4; i++) {
        const int row = wrow * 64 + i * 16 + (lane & 15);
        af[i] = *(const short8*)&As[row * 64 + (kb ^ ((row & 7) * 8))];
      }
#pragma unroll
      for (int j = 0; j < 4; j++) {
        const int nr = wcol * 64 + j * 16 + (lane & 15);
        bfr[j] = *(const short8*)&Bs[nr * 64 + (kb ^ ((nr & 7) * 8))];
      }
#pragma unroll
      for (int i = 0; i < 4; i++)
#pragma unroll
        for (int j = 0; j < 4; j++)
          acc[i][j] = __builtin_amdgcn_mfma_f32_16x16x32_bf16(af[i], bfr[j], acc[i][j], 0, 0, 0);
    }
  }

  if (CKIND == 0) {
    __syncthreads();
    u16* Cs = smem;  // 128x128 u16 = 32 KiB
#pragma unroll
    for (int i = 0; i < 4; i++) {
#pragma unroll
      for (int j = 0; j < 4; j++) {
        const int col = wcol * 64 + j * 16 + (lane & 15);
        const float bc = bias[n0 + col];
#pragma unroll
        for (int r = 0; r < 4; r++) {
          const int row = wrow * 64 + i * 16 + ((lane >> 4) << 2) + r;
          Cs[row * 128 + (col ^ ((row & 7) * 8))] = f2bf(acc[i][j][r] + bc);
        }
      }
    }
    __syncthreads();
    u16* C = (u16*)Cp;
#pragma unroll
    for (int p = 0; p < 8; p++) {
      const int row = arow_t + p * 16;
      const int g = (tid & 15) * 8;
      *(short8*)(C + (size_t)(m0 + row) * 256 + n0 + g) =
          *(const short8*)&Cs[row * 128 + (g ^ ((row & 7) * 8))];
    }
  } else {
    float* C = (float*)Cp;
#pragma unroll
    for (int i = 0; i < 4; i++) {
      const int rbase = m0 + wrow * 64 + i * 16 + ((lane >> 4) << 2);
#pragma unroll
      for (int j = 0; j < 4; j++) {
        const int col = n0 + wcol * 64 + j * 16 + (lane & 15);
        if (col < Ncols) {
          const float bc = bias[col];
#pragma unroll
          for (int r = 0; r < 4; r++) {
            const int row = rbase + r;
            if (!GUARD || row < M)
              C[(size_t)row * Ncols + col] = acc[i][j][r] + bc;
          }
        }
      }
    }
  }
}

// ---------------------------------------------------------------------------
// fp32 GEMM for position-critical offsets/logits (verified R1 kernel).
// ---------------------------------------------------------------------------
#define BM 128
#define BN 128
#define BK 8
#define TM 8
#define TN 8
__global__ __launch_bounds__(256) void gemm_f32(
    const float* __restrict__ A, const float* __restrict__ W,
    const float* __restrict__ bias, float* __restrict__ C,
    int M, int N, int K) {
  __shared__ float As[BK][BM + 4];
  __shared__ float Bs[BK][BN + 4];
  const int tid = threadIdx.x;
  const int bm = blockIdx.y, bn = blockIdx.x;
  const int tr = tid >> 4, tc = tid & 15;

  float acc[TM][TN];
#pragma unroll
  for (int i = 0; i < TM; i++)
#pragma unroll
    for (int j = 0; j < TN; j++) acc[i][j] = 0.f;

  int arow = bm * BM + (tid >> 1);
  int arow_c = arow < M ? arow : (M - 1);
  const float* Aptr = A + (size_t)arow_c * K + ((tid & 1) << 2);
  int bcol = bn * BN + ((tid & 31) << 2);
  const bool bvalid = bcol < N;
  const float* Wptr = W + (size_t)(tid >> 5) * N + bcol;

  for (int k0 = 0; k0 < K; k0 += BK) {
    float4 av = *(const float4*)(Aptr + k0);
    float4 bv = bvalid ? *(const float4*)(Wptr + (size_t)k0 * N)
                       : make_float4(0.f, 0.f, 0.f, 0.f);
    __syncthreads();
    As[(tid & 1) * 4 + 0][tid >> 1] = av.x;
    As[(tid & 1) * 4 + 1][tid >> 1] = av.y;
    As[(tid & 1) * 4 + 2][tid >> 1] = av.z;
    As[(tid & 1) * 4 + 3][tid >> 1] = av.w;
    *(float4*)&Bs[tid >> 5][(tid & 31) << 2] = bv;
    __syncthreads();
#pragma unroll
    for (int k = 0; k < BK; k++) {
      float ar[TM], br[TN];
      *(float4*)&ar[0] = *(const float4*)&As[k][tr * TM];
      *(float4*)&ar[4] = *(const float4*)&As[k][tr * TM + 4];
      *(float4*)&br[0] = *(const float4*)&Bs[k][tc * TN];
      *(float4*)&br[4] = *(const float4*)&Bs[k][tc * TN + 4];
#pragma unroll
      for (int i = 0; i < TM; i++)
#pragma unroll
        for (int j = 0; j < TN; j++) acc[i][j] = fmaf(ar[i], br[j], acc[i][j]);
    }
  }

#pragma unroll
  for (int i = 0; i < TM; i++) {
    int row = bm * BM + tr * TM + i;
    if (row >= M) continue;
    float* Crow = C + (size_t)row * N;
#pragma unroll
    for (int j = 0; j < TN; j += 4) {
      int col = bn * BN + tc * TN + j;
      if (col < N) {
        float4 o;
        o.x = acc[i][j + 0] + bias[col + 0];
        o.y = acc[i][j + 1] + bias[col + 1];
        o.z = acc[i][j + 2] + bias[col + 2];
        o.w = acc[i][j + 3] + bias[col + 3];
        *(float4*)(Crow + col) = o;
      }
    }
  }
}

// ---------------------------------------------------------------------------
// Branch-free sampling, 4 channels/lane, 4 queries/block. attn bf16 (padded).
// ---------------------------------------------------------------------------
__global__ __launch_bounds__(256) void ms_deform_fused(
    const u16* __restrict__ value,    // (B*8400, 256) bf16
    const float* __restrict__ offaw,  // (4800, 288)
    const float* __restrict__ refp,   // (16,300,3,4)
    u16* __restrict__ attn_out) {     // (4864, 256) bf16
  const int q_local = threadIdx.x >> 6;
  const int bq = blockIdx.x * 4 + q_local;   // grid 1216 -> 0..4863
  const int h = (threadIdx.x >> 3) & 7;
  const int d4 = (threadIdx.x & 7) * 4;
  u16* outp = attn_out + (size_t)bq * 256 + h * 32 + d4;
  if (bq >= 4800) {
    short4v z = {0, 0, 0, 0};
    *(short4v*)outp = z;
    return;
  }
  const int b = bq / 300;
  const float* row = offaw + (size_t)bq * 288;

  float lg[12];
#pragma unroll
  for (int j = 0; j < 12; j++) lg[j] = row[192 + h * 12 + j];
  float m = lg[0];
#pragma unroll
  for (int j = 1; j < 12; j++) m = fmaxf(m, lg[j]);
  float s = 0.f;
#pragma unroll
  for (int j = 0; j < 12; j++) { lg[j] = __expf(lg[j] - m); s += lg[j]; }
  const float inv = 1.f / s;

  const int lvlW[3] = {80, 40, 20};
  const int lvlS[3] = {0, 6400, 8000};
  const float* ref = refp + (size_t)bq * 12;
  float acc0 = 0.f, acc1 = 0.f, acc2 = 0.f, acc3 = 0.f;

#pragma unroll
  for (int l = 0; l < 3; l++) {
    const int Ws = lvlW[l];
    const float r0 = ref[l * 4 + 0], r1 = ref[l * 4 + 1];
    const float r2 = ref[l * 4 + 2], r3 = ref[l * 4 + 3];
    const u16* vbase = value + ((size_t)(b * 8400 + lvlS[l]) * 256) + h * 32 + d4;
#pragma unroll
    for (int p = 0; p < 4; p++) {
      const float ox = row[h * 24 + l * 8 + p * 2 + 0];
      const float oy = row[h * 24 + l * 8 + p * 2 + 1];
      const float x = (r0 + ox * 0.125f * r2) * (float)Ws - 0.5f;
      const float y = (r1 + oy * 0.125f * r3) * (float)Ws - 0.5f;
      const float x0f = floorf(x), y0f = floorf(y);
      const float wx = x - x0f, wy = y - y0f;
      const int x0 = (int)x0f, y0 = (int)y0f;
      const int x0c = min(max(x0, 0), Ws - 1), x1c = min(max(x0 + 1, 0), Ws - 1);
      const int y0c = min(max(y0, 0), Ws - 1), y1c = min(max(y0 + 1, 0), Ws - 1);
      const float fx0 = ((unsigned)x0 < (unsigned)Ws) ? 1.f : 0.f;
      const float fx1 = ((unsigned)(x0 + 1) < (unsigned)Ws) ? 1.f : 0.f;
      const float fy0 = ((unsigned)y0 < (unsigned)Ws) ? 1.f : 0.f;
      const float fy1 = ((unsigned)(y0 + 1) < (unsigned)Ws) ? 1.f : 0.f;
      const short4v v00 = *(const short4v*)(vbase + (size_t)(y0c * Ws + x0c) * 256);
      const short4v v01 = *(const short4v*)(vbase + (size_t)(y0c * Ws + x1c) * 256);
      const short4v v10 = *(const short4v*)(vbase + (size_t)(y1c * Ws + x0c) * 256);
      const short4v v11 = *(const short4v*)(vbase + (size_t)(y1c * Ws + x1c) * 256);
      const float pw = lg[l * 4 + p] * inv;
      const float w00 = (1.f - wx) * (1.f - wy) * fy0 * fx0 * pw;
      const float w01 = wx * (1.f - wy) * fy0 * fx1 * pw;
      const float w10 = (1.f - wx) * wy * fy1 * fx0 * pw;
      const float w11 = wx * wy * fy1 * fx1 * pw;
      acc0 = fmaf(w00, bf2f((u16)v00[0]), acc0);
      acc1 = fmaf(w00, bf2f((u16)v00[1]), acc1);
      acc2 = fmaf(w00, bf2f((u16)v00[2]), acc2);
      acc3 = fmaf(w00, bf2f((u16)v00[3]), acc3);
      acc0 = fmaf(w01, bf2f((u16)v01[0]), acc0);
      acc1 = fmaf(w01, bf2f((u16)v01[1]), acc1);
      acc2 = fmaf(w01, bf2f((u16)v01[2]), acc2);
      acc3 = fmaf(w01, bf2f((u16)v01[3]), acc3);
      acc0 = fmaf(w10, bf2f((u16)v10[0]), acc0);
      acc1 = fmaf(w10, bf2f((u16)v10[1]), acc1);
      acc2 = fmaf(w10, bf2f((u16)v10[2]), acc2);
      acc3 = fmaf(w10, bf2f((u16)v10[3]), acc3);
      acc0 = fmaf(w11, bf2f((u16)v11[0]), acc0);
      acc1 = fmaf(w11, bf2f((u16)v11[1]), acc1);
      acc2 = fmaf(w11, bf2f((u16)v11[2]), acc2);
      acc3 = fmaf(w11, bf2f((u16)v11[3]), acc3);
    }
  }
  short4v o;
  o[0] = (short)f2bf(acc0);
  o[1] = (short)f2bf(acc1);
  o[2] = (short)f2bf(acc2);
  o[3] = (short)f2bf(acc3);
  *(short4v*)outp = o;
}

extern "C" void kernel_launch(void* const* d_in, const int* in_sizes, int n_in,
                              void* d_out, int out_size, void* d_ws, size_t ws_size,
                              hipStream_t stream) {
  const float* hidden = (const float*)d_in[0];
  const float* ehs    = (const float*)d_in[1];
  const float* refp   = (const float*)d_in[2];
  const float* vw     = (const float*)d_in[3];
  const float* vb     = (const float*)d_in[4];
  const float* offw   = (const float*)d_in[5];
  const float* offb   = (const float*)d_in[6];
  const float* attnw  = (const float*)d_in[7];
  const float* attnb  = (const float*)d_in[8];
  const float* outw   = (const float*)d_in[9];
  const float* outb   = (const float*)d_in[10];
  float* out = (float*)d_out;

  u16* value = (u16*)d_ws;                    // 34406400 u16
  u16* attn  = value + 34406400;              // 1245184 u16
  u16* WtV   = attn + 1245184;                // 65536
  u16* outwT = WtV + 65536;                   // 65536
  float* Wcat  = (float*)(outwT + 65536);     // 73728 f32
  float* bcat  = Wcat + 73728;                // 512
  float* offaw = bcat + 512;                  // 1382400

  prep_weights<<<384, 256, 0, stream>>>(vw, offw, attnw, offb, attnb, outw,
                                        WtV, outwT, Wcat, bcat);
  // value = ehs @ vw + vb  -> bf16 (MFMA)
  gemm_mfma<0, 0, false><<<dim3(2, 1050), 256, 0, stream>>>(
      ehs, WtV, vb, value, 134400, 256);
  // offaw = hidden @ [offw|attnw] + bcat -> f32 (position-critical: fp32 VALU)
  gemm_f32<<<dim3(3, 38), 256, 0, stream>>>(hidden, Wcat, bcat, offaw, 4800, 288, 256);
  // sampling -> attn bf16 (padded to 4864 rows)
  ms_deform_fused<<<1216, 256, 0, stream>>>(value, offaw, refp, attn);
  // out = attn @ outw + outb -> f32 (MFMA)
  gemm_mfma<1, 1, true><<<dim3(2, 38), 256, 0, stream>>>(
      attn, outwT, outb, out, 4800, 256);
}